// Round 1
// baseline (342.316 us; speedup 1.0000x reference)
//
#include <hip/hip_runtime.h>
#include <hip/hip_bf16.h>

#define B_  8
#define S_  2048
#define D_  1024
#define H_  8
#define HD_ 128
#define P_  32
#define BS_ (B_*S_)
#define PI_F 3.14159265358979323846f

typedef unsigned short u16;
typedef __attribute__((ext_vector_type(4))) float  f32x4;
typedef __attribute__((ext_vector_type(8))) __bf16 bf16x8;

__device__ __forceinline__ u16 f2b(float f) {
  __hip_bfloat16 h = __float2bfloat16(f);
  return __builtin_bit_cast(u16, h);
}
__device__ __forceinline__ float b2f(u16 b) {
  return __bfloat162float(__builtin_bit_cast(__hip_bfloat16, b));
}

__device__ __forceinline__ void gload_lds16(const void* g, void* l) {
  auto gp = (const __attribute__((address_space(1))) unsigned int*)g;
  auto lp = (__attribute__((address_space(3))) unsigned int*)l;
  __builtin_amdgcn_global_load_lds(gp, lp, 16, 0, 0);
}

// ---------------- x -> bf16 ----------------
__global__ __launch_bounds__(256) void cvt_x_kernel(const float* __restrict__ x,
                                                    u16* __restrict__ xb, int n4) {
  int i = blockIdx.x * blockDim.x + threadIdx.x;
  for (; i < n4; i += gridDim.x * blockDim.x) {
    float4 v = reinterpret_cast<const float4*>(x)[i];
    ushort4 o;
    o.x = f2b(v.x); o.y = f2b(v.y); o.z = f2b(v.z); o.w = f2b(v.w);
    reinterpret_cast<ushort4*>(xb)[i] = o;
  }
}

// ---------------- weights -> bf16 (fold cos(pi*f) into W_proj) ----------------
__global__ __launch_bounds__(256) void cvt_w_kernel(const float* __restrict__ Wproj,
                                                    const float* __restrict__ freqs,
                                                    const float* __restrict__ Wo,
                                                    u16* __restrict__ Wt1,
                                                    u16* __restrict__ Wob) {
  int i = blockIdx.x * blockDim.x + threadIdx.x;
  const int total = D_ * D_;
  for (; i < total; i += gridDim.x * blockDim.x) {
    int n = i >> 10;                       // row = h*128+e
    float c = cosf(PI_F * freqs[n]);
    Wt1[i] = f2b(Wproj[i] * c);
    Wob[i] = f2b(Wo[i]);
  }
}

// ---------------- bf16 GEMM  C(MxN) = A(MxK) * B(NxK)^T, bf16 out ----------------
// m97 structure: 128x128 tile, BK=32, 4 waves (2x2 of 64x64), global_load_lds w16
__global__ __launch_bounds__(256) void gemm_bt(const u16* __restrict__ A,
                                               const u16* __restrict__ Bm,
                                               u16* __restrict__ C,
                                               int M, int N, int K) {
  __shared__ __align__(16) u16 As[128 * 32];
  __shared__ __align__(16) u16 Bs[128 * 32];
  const int tid = threadIdx.x;
  const int bm0 = blockIdx.x * 128;
  const int bn0 = blockIdx.y * 128;
  const int w = tid >> 6, l = tid & 63;
  const int wr = w >> 1, wc = w & 1;
  const int lr = l & 15, lk = (l >> 4) * 8;

  f32x4 acc[4][4] = {};

  const int arow = tid >> 2;            // 0..63 (round 0), +64 for round 1
  const int acol = (tid & 3) * 8;
  const u16* Ap = A + (long)(bm0 + arow) * K + acol;
  const u16* Bp = Bm + (long)(bn0 + arow) * K + acol;

  for (int k0 = 0; k0 < K; k0 += 32) {
    gload_lds16(Ap + k0,            As + tid * 8);
    gload_lds16(Ap + (long)64 * K + k0, As + 2048 + tid * 8);
    gload_lds16(Bp + k0,            Bs + tid * 8);
    gload_lds16(Bp + (long)64 * K + k0, Bs + 2048 + tid * 8);
    __syncthreads();

    bf16x8 af[4], bfr[4];
#pragma unroll
    for (int m = 0; m < 4; ++m)
      af[m] = *reinterpret_cast<const bf16x8*>(&As[(wr * 64 + m * 16 + lr) * 32 + lk]);
#pragma unroll
    for (int n = 0; n < 4; ++n)
      bfr[n] = *reinterpret_cast<const bf16x8*>(&Bs[(wc * 64 + n * 16 + lr) * 32 + lk]);
#pragma unroll
    for (int m = 0; m < 4; ++m)
#pragma unroll
      for (int n = 0; n < 4; ++n)
        acc[m][n] = __builtin_amdgcn_mfma_f32_16x16x32_bf16(af[m], bfr[n], acc[m][n], 0, 0, 0);
    __syncthreads();
  }

  // epilogue: C/D layout row=(l>>4)*4+j, col=l&15 (m89-verified)
  const int or0 = bm0 + wr * 64 + (l >> 4) * 4;
  const int oc0 = bn0 + wc * 64 + (l & 15);
#pragma unroll
  for (int m = 0; m < 4; ++m)
#pragma unroll
    for (int n = 0; n < 4; ++n)
#pragma unroll
      for (int j = 0; j < 4; ++j) {
        int row = or0 + m * 16 + j;
        int col = oc0 + n * 16;
        C[(long)row * N + col] = f2b(acc[m][n][j]);
      }
}

// ---------------- column sums of heads over S (into zeroed f32 hm) ----------------
__global__ __launch_bounds__(256) void hm_kernel(const u16* __restrict__ heads,
                                                 float* __restrict__ hm) {
  // grid = 256: b(8) x colchunk(4) x schunk(8)
  int b  = blockIdx.x >> 5;
  int cc = (blockIdx.x >> 3) & 3;
  int sc = blockIdx.x & 7;
  int col = cc * 256 + threadIdx.x;
  const u16* p = heads + ((long)(b * S_ + sc * 256)) * D_ + col;
  float s = 0.f;
  for (int i = 0; i < 256; ++i) s += b2f(p[(long)i * D_]);
  atomicAdd(&hm[b * D_ + col], s);
}

// ---------------- coef MLP (tiny, 1 block) ----------------
__global__ __launch_bounds__(512) void coef_kernel(const float* __restrict__ hm,
                                                   const float* __restrict__ Wp,
                                                   const float* __restrict__ bp,
                                                   const float* __restrict__ w1,
                                                   const float* __restrict__ b1,
                                                   const float* __restrict__ w2,
                                                   const float* __restrict__ b2,
                                                   float* __restrict__ coef) {
  __shared__ float pm_s[B_ * H_ * P_];   // 2048
  int t = threadIdx.x;
  for (int i = t; i < B_ * H_ * P_; i += 512) {
    int b = i >> 8, h = (i >> 5) & 7, p = i & 31;
    float acc = bp[h * P_ + p];
    const float* hmp = hm + b * D_ + h * HD_;
    const float* wp = Wp + (h * P_ + p) * HD_;
#pragma unroll 4
    for (int e = 0; e < HD_; ++e) acc += (hmp[e] * (1.0f / S_)) * wp[e];
    pm_s[i] = tanhf(acc);
  }
  __syncthreads();
  if (t < 64) {
    float ss = 0.f;
    for (int p = 0; p < P_; ++p) { float v = pm_s[t * P_ + p]; ss += v * v; }
    float inv = 1.0f / fmaxf(sqrtf(ss), 1e-12f);
    for (int p = 0; p < P_; ++p) pm_s[t * P_ + p] *= inv;
  }
  __syncthreads();
  {
    int b = t >> 6, i = (t >> 3) & 7, j = t & 7;
    float dp = 0.f;
    for (int p = 0; p < P_; ++p)
      dp += pm_s[(b * H_ + i) * P_ + p] * pm_s[(b * H_ + j) * P_ + p];
    float acc = b2[0];
#pragma unroll
    for (int k = 0; k < 16; ++k) {
      float z = dp * w1[k] + b1[k];
      float g = 0.5f * z * (1.0f + erff(z * 0.70710678118654752f));  // exact gelu
      acc += g * w2[k];
    }
    float sp = (acc > 20.f) ? acc : log1pf(expf(acc));               // softplus
    coef[t] = (i == j) ? 0.f : 0.1f / (1.0f + sp);
  }
}

// ---------------- head mixing: mixed = heads + scale(s) * coef x heads ----------------
__global__ __launch_bounds__(256) void mix_kernel(const u16* __restrict__ heads,
                                                  const float* __restrict__ coef,
                                                  u16* __restrict__ mixed) {
  __shared__ float row[D_];
  __shared__ float cf[64];
  const int r = blockIdx.x;
  const int b = r >> 11, s = r & 2047;
  const int t = threadIdx.x;
  if (t < 64) cf[t] = coef[b * 64 + t];
  const u16* hp = heads + (long)r * D_;
  ushort4 hv = reinterpret_cast<const ushort4*>(hp)[t];
#pragma unroll
  for (int q = 0; q < 4; ++q) row[t * 4 + q] = b2f(((u16*)&hv)[q]);
  __syncthreads();
  const float scale = (float)(s + 1) * (1.0f / S_);
  const int d0 = t * 4;
  const int h = d0 >> 7;
  float ch[8];
#pragma unroll
  for (int j = 0; j < 8; ++j) ch[j] = cf[h * 8 + j];
  ushort4 o;
#pragma unroll
  for (int q = 0; q < 4; ++q) {
    int d = d0 + q, e = d & 127;
    float tr = 0.f;
#pragma unroll
    for (int j = 0; j < 8; ++j) tr += ch[j] * row[j * 128 + e];
    ((u16*)&o)[q] = f2b(row[d] + scale * tr);
  }
  reinterpret_cast<ushort4*>(mixed + (long)r * D_)[t] = o;
}

// ---------------- bias + residual + LayerNorm ----------------
__global__ __launch_bounds__(256) void ln_kernel(const u16* __restrict__ ypre,
                                                 const float* __restrict__ x,
                                                 const float* __restrict__ bo,
                                                 const float* __restrict__ g,
                                                 const float* __restrict__ be,
                                                 float* __restrict__ out) {
  const int r = blockIdx.x, t = threadIdx.x;
  const u16* yp = ypre + (long)r * D_;
  const float* xp = x + (long)r * D_;
  const int d0 = t * 4;
  float4 xv = reinterpret_cast<const float4*>(xp)[t];
  ushort4 yv = reinterpret_cast<const ushort4*>(yp)[t];
  float v[4];
  float s = 0.f, ss = 0.f;
#pragma unroll
  for (int q = 0; q < 4; ++q) {
    float y = b2f(((u16*)&yv)[q]) + bo[d0 + q] + ((const float*)&xv)[q];
    v[q] = y; s += y; ss += y * y;
  }
#pragma unroll
  for (int off = 32; off; off >>= 1) {
    s += __shfl_xor(s, off);
    ss += __shfl_xor(ss, off);
  }
  __shared__ float rs[4], rss[4];
  int w = t >> 6;
  if ((t & 63) == 0) { rs[w] = s; rss[w] = ss; }
  __syncthreads();
  s = rs[0] + rs[1] + rs[2] + rs[3];
  ss = rss[0] + rss[1] + rss[2] + rss[3];
  float mu = s * (1.0f / D_);
  float var = ss * (1.0f / D_) - mu * mu;
  float rstd = rsqrtf(var + 1e-5f);
  float4 ov;
#pragma unroll
  for (int q = 0; q < 4; ++q)
    ((float*)&ov)[q] = (v[q] - mu) * rstd * g[d0 + q] + be[d0 + q];
  reinterpret_cast<float4*>(out + (long)r * D_)[t] = ov;
}

extern "C" void kernel_launch(void* const* d_in, const int* in_sizes, int n_in,
                              void* d_out, int out_size, void* d_ws, size_t ws_size,
                              hipStream_t stream) {
  (void)in_sizes; (void)n_in; (void)out_size; (void)ws_size;
  const float* x     = (const float*)d_in[0];
  const float* Wproj = (const float*)d_in[1];
  const float* freqs = (const float*)d_in[2];
  const float* Wp    = (const float*)d_in[3];
  const float* bp    = (const float*)d_in[4];
  const float* w1    = (const float*)d_in[5];
  const float* b1    = (const float*)d_in[6];
  const float* w2    = (const float*)d_in[7];
  const float* b2    = (const float*)d_in[8];
  const float* Wo    = (const float*)d_in[9];
  const float* bo    = (const float*)d_in[10];
  const float* ln_g  = (const float*)d_in[11];
  const float* ln_b  = (const float*)d_in[12];
  float* out = (float*)d_out;

  char* ws = (char*)d_ws;
  u16*   xbf   = (u16*)ws;                         // 33.55 MB ; later: mixed
  u16*   heads = (u16*)(ws + 33554432);            // 33.55 MB ; later: y_pre (bf16)
  u16*   Wt1   = (u16*)(ws + 67108864);            // 2 MB
  u16*   Wob   = (u16*)(ws + 69206016);            // 2 MB
  float* hm    = (float*)(ws + 71303168);          // 32 KB
  float* coef  = (float*)(ws + 71335936);          // 2 KB

  hipMemsetAsync(hm, 0, B_ * D_ * sizeof(float), stream);

  cvt_x_kernel<<<2048, 256, 0, stream>>>(x, xbf, BS_ * D_ / 4);
  cvt_w_kernel<<<1024, 256, 0, stream>>>(Wproj, freqs, Wo, Wt1, Wob);

  dim3 g1(BS_ / 128, D_ / 128);   // (128, 8)
  gemm_bt<<<g1, 256, 0, stream>>>(xbf, Wt1, heads, BS_, D_, D_);

  hm_kernel<<<256, 256, 0, stream>>>(heads, hm);
  coef_kernel<<<1, 512, 0, stream>>>(hm, Wp, bp, w1, b1, w2, b2, coef);
  mix_kernel<<<BS_, 256, 0, stream>>>(heads, coef, xbf /* mixed (aliases xbf) */);

  gemm_bt<<<g1, 256, 0, stream>>>(xbf, Wob, heads /* y_pre bf16 (aliases heads) */, BS_, D_, D_);

  ln_kernel<<<BS_, 256, 0, stream>>>(heads, x, bo, ln_g, ln_b, out);
}